// Round 3
// baseline (506.756 us; speedup 1.0000x reference)
//
#include <hip/hip_runtime.h>
#include <cstdint>
#include <cstddef>

typedef short short8 __attribute__((ext_vector_type(8)));
typedef float f32x4 __attribute__((ext_vector_type(4)));
typedef float f32x16 __attribute__((ext_vector_type(16)));
typedef unsigned short us4 __attribute__((ext_vector_type(4)));

// ---------- helpers ----------
__device__ __forceinline__ unsigned short f2bf(float f) {
  unsigned int u = __float_as_uint(f);
  unsigned int r = (u + 0x7fffu + ((u >> 16) & 1u)) >> 16;  // RNE
  return (unsigned short)r;
}
// v_exp_f32: D = 2^S0 (builtin; __exp2f collides with glibc math.h here)
__device__ __forceinline__ float exp2_fast(float x) {
  return __builtin_amdgcn_exp2f(x);
}
// gfx950 packed f32->bf16 RNE convert: D[15:0]=bf16(a), D[31:16]=bf16(b)
__device__ __forceinline__ unsigned int cvt_pk_bf16(float a, float b) {
  unsigned int d;
  asm("v_cvt_pk_bf16_f32 %0, %1, %2" : "=v"(d) : "v"(a), "v"(b));
  return d;
}
// v_permlane32_swap_b32 a, b : a(upper 32 lanes) <-> b(lower 32 lanes).
__device__ __forceinline__ void permlane32_swap2(unsigned int& a, unsigned int& b) {
  asm("v_permlane32_swap_b32 %0, %1" : "+v"(a), "+v"(b));
}
// async global->LDS, 16B per lane. LDS dest = wave-uniform base + lane*16.
__device__ __forceinline__ void gload_lds16(const void* g, void* l) {
  auto gp = reinterpret_cast<const __attribute__((address_space(1))) char*>(
      reinterpret_cast<uintptr_t>(g));
  auto lp = reinterpret_cast<__attribute__((address_space(3))) char*>(
      reinterpret_cast<uintptr_t>(l));
  __builtin_amdgcn_global_load_lds(gp, lp, 16, 0, 0);
}

// ---------- weight reconstruction: w' = (LM@RM + W) * F * scale (bf16), b' = b*F*scale ----------
__global__ __launch_bounds__(256) void prep_weights(
    const float* __restrict__ W, const float* __restrict__ bias,
    const float* __restrict__ LM, const float* __restrict__ RM,
    const float* __restrict__ F, float scale,
    unsigned short* __restrict__ Wout, float* __restrict__ bout) {
  const int o = blockIdx.x;      // output row 0..1023
  const int tid = threadIdx.x;   // 256
  __shared__ float lm[64];
  if (tid < 64) lm[tid] = LM[o * 64 + tid];
  __syncthreads();
  const float f = F[o] * scale;
#pragma unroll
  for (int j = 0; j < 4; ++j) {
    const int i = tid + j * 256;
    float acc = W[o * 1024 + i];
#pragma unroll 16
    for (int k = 0; k < 64; ++k) acc = fmaf(lm[k], RM[k * 1024 + i], acc);
    Wout[o * 1024 + i] = f2bf(acc * f);
  }
  if (tid == 0) bout[o] = bias[o] * f;
}

// ---------- f32 -> bf16 cast ----------
__global__ __launch_bounds__(256) void cast_x(const float* __restrict__ x,
                                              unsigned short* __restrict__ y, int n4) {
  const int i = blockIdx.x * 256 + threadIdx.x;
  if (i >= n4) return;
  f32x4 v = *(const f32x4*)(x + (size_t)i * 4);
  us4 o;
  o[0] = f2bf(v[0]); o[1] = f2bf(v[1]); o[2] = f2bf(v[2]); o[3] = f2bf(v[3]);
  *(us4*)(y + (size_t)i * 4) = o;
}

// ---------- GEMM: C[m][n] = sum_k A[m][k]*Bw[n][k] + bias[n] ----------
// R8: double-buffered LDS (T3-min), single barrier/iter, counted-drain vmcnt(0)
// placed one full compute phase after issue (≈free), setprio around MFMA (T5),
// 1D grid with XCD-chunked decode (T1): each XCD gets 16 contiguous bm panels
// (4MB = its L2) reused across all bn.
// 128x128 block tile, BK=64, 4 waves each 64x64 (4x4 of 16x16x32 mfma).
// LDS XOR-swizzled: 16B chunk c of row r stored at chunk position c^(r&7).
// MODE 0: scatter to qkv bf16: q,k -> [bh][s][d]; v -> TRANSPOSED [bh][d][s].
// MODE 1: f32 row-major out.
template <int MODE>
__global__ __launch_bounds__(256) void gemm_bt(const unsigned short* __restrict__ A,
                                               const unsigned short* __restrict__ Bw,
                                               const float* __restrict__ bias,
                                               void* __restrict__ Cout,
                                               int M, int N, int K) {
  __shared__ unsigned short sA[2][128 * 64];
  __shared__ unsigned short sB[2][128 * 64];
  const int tid = threadIdx.x;
  const int w = tid >> 6;
  const int lane = tid & 63;
  const int quad = lane >> 4;
  const int ln = lane & 15;
  // XCD-chunked decode: hw xcd = bid&7; chunk of nwg/8 contiguous wgids per XCD.
  const int nbn = N >> 7;
  const int cpx = (int)gridDim.x >> 3;
  const int wgid = ((int)blockIdx.x & 7) * cpx + ((int)blockIdx.x >> 3);
  const int bm = wgid / nbn, bn = wgid - bm * nbn;
  const int wm = w >> 1, wn = w & 1;

  f32x4 acc[4][4];
#pragma unroll
  for (int a = 0; a < 4; ++a)
#pragma unroll
    for (int b = 0; b < 4; ++b) acc[a][b] = (f32x4){0.f, 0.f, 0.f, 0.f};

  const size_t Kb = (size_t)K * 2;
  const char* Agb = (const char*)A + (size_t)bm * 128 * Kb;
  const char* Bgb = (const char*)Bw + (size_t)bn * 128 * Kb;
  const int sw = ln & 7;
  const int nt = K >> 6;

  // stage K-tile (64 k) starting at k-offset k0*2 bytes into buffer buf
  auto stage = [&](int k0, int buf) {
    char* sAd = (char*)sA + buf * 16384;
    char* sBd = (char*)sB + buf * 16384;
#pragma unroll
    for (int i = 0; i < 4; ++i) {
      const int Lb = w * 4096 + i * 1024 + lane * 16;  // linear byte in tile
      const int r = Lb >> 7;                           // tile row (128B rows)
      const int c = (Lb >> 4) & 7;                     // LDS chunk slot
      const int cb = ((c ^ (r & 7)) * 16);             // global chunk (unswizzle)
      gload_lds16(Agb + (size_t)r * Kb + (size_t)k0 * 2 + cb, sAd + Lb);
      gload_lds16(Bgb + (size_t)r * Kb + (size_t)k0 * 2 + cb, sBd + Lb);
    }
  };

  stage(0, 0);  // prologue

  for (int t = 0; t < nt; ++t) {
    const int cur = t & 1;
    // stage(t) was issued one full compute phase ago -> drain is ~free.
    asm volatile("s_waitcnt vmcnt(0)" ::: "memory");
    __builtin_amdgcn_s_barrier();  // stage(t) visible; buf[cur^1] free
    asm volatile("" ::: "memory");
    if (t + 1 < nt) stage((t + 1) << 6, cur ^ 1);

    const char* sAc = (const char*)sA + cur * 16384;
    const char* sBc = (const char*)sB + cur * 16384;
#pragma unroll
    for (int kk = 0; kk < 2; ++kk) {
      short8 af[4], bfv[4];
#pragma unroll
      for (int t4 = 0; t4 < 4; ++t4) {
        const int ch = ((kk * 4 + quad) ^ sw) * 16;
        af[t4]  = *(const short8*)(sAc + (wm * 64 + t4 * 16 + ln) * 128 + ch);
        bfv[t4] = *(const short8*)(sBc + (wn * 64 + t4 * 16 + ln) * 128 + ch);
      }
      __builtin_amdgcn_s_setprio(1);
#pragma unroll
      for (int mt = 0; mt < 4; ++mt)
#pragma unroll
        for (int ntc = 0; ntc < 4; ++ntc)
          acc[mt][ntc] = __builtin_amdgcn_mfma_f32_16x16x32_bf16(af[mt], bfv[ntc], acc[mt][ntc], 0, 0, 0);
      __builtin_amdgcn_s_setprio(0);
    }
  }

  // epilogue. C/D layout: col = ln, row = quad*4 + reg (measured m89/m91)
  if (MODE == 0) {
    unsigned short* out = (unsigned short*)Cout;
#pragma unroll
    for (int mt = 0; mt < 4; ++mt) {
#pragma unroll
      for (int ntc = 0; ntc < 4; ++ntc) {
        const int gn = bn * 128 + wn * 64 + ntc * 16 + ln;
        const float bv = bias[gn];
        const int pidx = gn >> 10, rem = gn & 1023;
        const int hh = rem >> 6, dd = rem & 63;
        const int gm0 = bm * 128 + wm * 64 + mt * 16 + quad * 4;
        const int bb = gm0 >> 10, ss0 = gm0 & 1023;
        if (pidx < 2) {
          // q,k: [p][b][h][s][d]
#pragma unroll
          for (int r = 0; r < 4; ++r) {
            const size_t off = ((((size_t)pidx * 16 + bb) * 16 + hh) * 1024 + (ss0 + r)) * 64 + dd;
            out[off] = f2bf(acc[mt][ntc][r] + bv);
          }
        } else {
          // v: transposed [b][h][d][s]; r -> consecutive s -> one 8B store
          us4 pk;
#pragma unroll
          for (int r = 0; r < 4; ++r) pk[r] = f2bf(acc[mt][ntc][r] + bv);
          const size_t off = (size_t)2 * 16777216 +
                             (((size_t)(bb * 16 + hh) * 64 + dd) * 1024 + ss0);
          *(us4*)(out + off) = pk;
        }
      }
    }
  } else {
    float* out = (float*)Cout;
#pragma unroll
    for (int mt = 0; mt < 4; ++mt) {
#pragma unroll
      for (int ntc = 0; ntc < 4; ++ntc) {
        const int gn = bn * 128 + wn * 64 + ntc * 16 + ln;
        const float bv = bias[gn];
#pragma unroll
        for (int r = 0; r < 4; ++r) {
          const int gm = bm * 128 + wm * 64 + mt * 16 + quad * 4 + r;
          out[(size_t)gm * N + gn] = acc[mt][ntc][r] + bv;
        }
      }
    }
  }
}

// ---------- flash attention, 32x32 MFMA, in-register P (T12), dbuf K/V ----------
// (unchanged from R7)
__global__ __launch_bounds__(256) void attn(const unsigned short* __restrict__ Qb,
                                            const unsigned short* __restrict__ Kb_,
                                            const unsigned short* __restrict__ VTb,
                                            unsigned short* __restrict__ ctx) {
  __shared__ unsigned short sK[2][64 * 64];   // [buf][kv][d], 128B rows, swizzled chunks
  __shared__ unsigned short sVT[2][64 * 64];  // [buf][d][kv], 128B rows, swizzled chunks
  const int tid = threadIdx.x;
  const int w = tid >> 6, lane = tid & 63;
  const int col = lane & 31, hi = lane >> 5;  // col = q (QK) / d (PV), hi = k-group
  const int sw7 = col & 7;                    // row&7 for swizzled LDS reads
  const int bid = blockIdx.x;
  const int xcd = bid & 7, qt = (bid >> 3) & 7, sbh = bid >> 6;
  const int bh = xcd * 32 + sbh;
  const int b = bh >> 4, h = bh & 15;

  // Q fragments (B-operand), loop-invariant: col=q, k = d = ks*16 + hi*8 + j
  short8 bq[4];
  {
    const unsigned short* Qg =
        Qb + ((size_t)bh * 1024 + (size_t)qt * 128 + w * 32 + col) * 64 + hi * 8;
#pragma unroll
    for (int ks = 0; ks < 4; ++ks) bq[ks] = *(const short8*)(Qg + ks * 16);
  }

  f32x16 accO[2];
#pragma unroll
  for (int nt = 0; nt < 2; ++nt)
#pragma unroll
    for (int r = 0; r < 16; ++r) accO[nt][r] = 0.f;
  float mrun = -3e38f, lrun = 0.f;

  const char* Kbase = (const char*)Kb_ + (size_t)bh * 131072;  // [kv=1024][d=64] bf16
  const char* Vbase = (const char*)VTb + (size_t)bh * 131072;  // [d=64][kv=1024] bf16

  // issue 4 gload_lds (K,V interleaved) for tile kt into buffer buf
  auto stage = [&](int kt, int buf) {
#pragma unroll
    for (int i = 0; i < 2; ++i) {
      const int Lb = w * 2048 + i * 1024 + lane * 16;
      const int r = Lb >> 7;            // tile row (128B rows)
      const int c = (Lb >> 4) & 7;      // LDS chunk slot
      const int cb = ((c ^ (r & 7)) * 16);
      gload_lds16(Kbase + (size_t)kt * 8192 + (size_t)r * 128 + cb, (char*)sK[buf] + Lb);
      gload_lds16(Vbase + (size_t)kt * 128 + (size_t)r * 2048 + cb, (char*)sVT[buf] + Lb);
    }
  };

  stage(0, 0);  // prologue: 4 loads in flight

  for (int kt = 0; kt < 16; ++kt) {
    const int cur = kt & 1;
    const char* sKb = (const char*)sK[cur];
    const char* sVb = (const char*)sVT[cur];

    // prefetch next tile into the other buffer (wraps harmlessly at kt=15)
    stage((kt + 1) & 15, cur ^ 1);
    // wait for OWN stage(kt) (4 oldest of 8 outstanding); prefetch stays in flight
    asm volatile("s_waitcnt vmcnt(4)" ::: "memory");
    __builtin_amdgcn_s_barrier();  // all waves' stage(kt) landed
    asm volatile("" ::: "memory");

    // S^T: A = K[kv][d], B = Q (col=q). accS[mt]: col=q, row=kv within mt*32.
    f32x16 accS[2];
#pragma unroll
    for (int mt = 0; mt < 2; ++mt)
#pragma unroll
      for (int r = 0; r < 16; ++r) accS[mt][r] = 0.f;
#pragma unroll
    for (int ks = 0; ks < 4; ++ks) {
      const int ch = (((2 * ks + hi) ^ sw7) * 16);
      const short8 ak0 = *(const short8*)(sKb + (col)*128 + ch);
      const short8 ak1 = *(const short8*)(sKb + (32 + col) * 128 + ch);
      __builtin_amdgcn_s_setprio(1);
      accS[0] = __builtin_amdgcn_mfma_f32_32x32x16_bf16(ak0, bq[ks], accS[0], 0, 0, 0);
      accS[1] = __builtin_amdgcn_mfma_f32_32x32x16_bf16(ak1, bq[ks], accS[1], 0, 0, 0);
      __builtin_amdgcn_s_setprio(0);
    }

    // online softmax (base-2; q pre-scaled by log2e/8). Lane: q=col,
    // kv = mt*32 + (r&3)+8*(r>>2)+4*hi.
    float tmax = -3e38f;
#pragma unroll
    for (int mt = 0; mt < 2; ++mt)
#pragma unroll
      for (int r = 0; r < 16; ++r) tmax = fmaxf(tmax, accS[mt][r]);
    tmax = fmaxf(tmax, __shfl_xor(tmax, 32));
    // defer-max: only rescale when the tile max meaningfully exceeds mrun.
    if (!__all(tmax <= mrun + 8.0f)) {
      const float mnew = fmaxf(mrun, tmax);
      const float alpha = exp2_fast(mrun - mnew);
      mrun = mnew;
      lrun *= alpha;
#pragma unroll
      for (int r = 0; r < 16; ++r) {
        const float ar = __shfl(alpha, (r & 3) + 8 * (r >> 2) + 4 * hi);
        accO[0][r] *= ar;
        accO[1][r] *= ar;
      }
    }
    const float m = mrun;

    // P chunks: exp2 -> bf16 pack -> permlane assemble A-frag -> PV MFMA.
    float psum = 0.f;
#pragma unroll
    for (int mt = 0; mt < 2; ++mt) {
#pragma unroll
      for (int c = 0; c < 2; ++c) {
        const int r0 = c * 8;
        const float e0 = exp2_fast(accS[mt][r0 + 0] - m);
        const float e1 = exp2_fast(accS[mt][r0 + 1] - m);
        const float e2 = exp2_fast(accS[mt][r0 + 2] - m);
        const float e3 = exp2_fast(accS[mt][r0 + 3] - m);
        const float e4 = exp2_fast(accS[mt][r0 + 4] - m);
        const float e5 = exp2_fast(accS[mt][r0 + 5] - m);
        const float e6 = exp2_fast(accS[mt][r0 + 6] - m);
        const float e7 = exp2_fast(accS[mt][r0 + 7] - m);
        psum += ((e0 + e1) + (e2 + e3)) + ((e4 + e5) + (e6 + e7));
        unsigned int x = cvt_pk_bf16(e0, e1);
        unsigned int y = cvt_pk_bf16(e2, e3);
        unsigned int z = cvt_pk_bf16(e4, e5);
        unsigned int t = cvt_pk_bf16(e6, e7);
        permlane32_swap2(x, z);  // -> x = dw0 (k=hi*8+0,1), z = dw2 (k=hi*8+4,5)
        permlane32_swap2(y, t);  // -> y = dw1 (k=hi*8+2,3), t = dw3 (k=hi*8+6,7)
        union { unsigned int u[4]; short8 v; } pa;
        pa.u[0] = x; pa.u[1] = y; pa.u[2] = z; pa.u[3] = t;
        const int cs = mt * 4 + c * 2 + hi;
        const int ch = ((cs ^ sw7) * 16);
        const short8 bv0 = *(const short8*)(sVb + (col)*128 + ch);
        const short8 bv1 = *(const short8*)(sVb + (32 + col) * 128 + ch);
        __builtin_amdgcn_s_setprio(1);
        accO[0] = __builtin_amdgcn_mfma_f32_32x32x16_bf16(pa.v, bv0, accO[0], 0, 0, 0);
        accO[1] = __builtin_amdgcn_mfma_f32_32x32x16_bf16(pa.v, bv1, accO[1], 0, 0, 0);
        __builtin_amdgcn_s_setprio(0);
      }
    }
    lrun += psum;  // per-lane partial (lanes l, l^32 hold disjoint kv halves)

    __builtin_amdgcn_s_barrier();  // all waves done reading buf[cur]
    asm volatile("" ::: "memory");
  }

  // epilogue: ctx[b][sg][h*64+d] bf16. accO: col=d (nt*32+col), row=q.
  float lt = lrun + __shfl_xor(lrun, 32);
  const float inv = 1.0f / lt;
#pragma unroll
  for (int r = 0; r < 16; ++r) {
    const int qr = (r & 3) + 8 * (r >> 2) + 4 * hi;
    const float iv = __shfl(inv, qr);  // lane qr holds inv for q=qr
    const int sg = qt * 128 + w * 32 + qr;
    const size_t base = ((size_t)(b * 1024 + sg)) * 1024 + h * 64;
    ctx[base + col] = f2bf(accO[0][r] * iv);
    ctx[base + 32 + col] = f2bf(accO[1][r] * iv);
  }
}

// ---------- launch ----------
extern "C" void kernel_launch(void* const* d_in, const int* in_sizes, int n_in,
                              void* d_out, int out_size, void* d_ws, size_t ws_size,
                              hipStream_t stream) {
  const float* hs  = (const float*)d_in[0];
  const float* Wq  = (const float*)d_in[1];
  const float* bq  = (const float*)d_in[2];
  const float* LMq = (const float*)d_in[3];
  const float* RMq = (const float*)d_in[4];
  const float* Fq  = (const float*)d_in[5];
  const float* Wk  = (const float*)d_in[6];
  const float* bk  = (const float*)d_in[7];
  const float* LMk = (const float*)d_in[8];
  const float* RMk = (const float*)d_in[9];
  const float* Fk  = (const float*)d_in[10];
  const float* Wv  = (const float*)d_in[11];
  const float* bv  = (const float*)d_in[12];
  const float* LMv = (const float*)d_in[13];
  const float* RMv = (const float*)d_in[14];
  const float* Fv  = (const float*)d_in[15];
  const float* Wo  = (const float*)d_in[16];
  const float* bo  = (const float*)d_in[17];
  const float* LMo = (const float*)d_in[18];
  const float* RMo = (const float*)d_in[19];
  const float* Fo  = (const float*)d_in[20];
  // d_in[21] = task (always 0 branch in reference)

  // workspace layout (all 16B aligned)
  char* p = (char*)d_ws;
  unsigned short* xbf  = (unsigned short*)p; p += (size_t)16384 * 1024 * 2;   // 33.5 MB
  unsigned short* Wqkv = (unsigned short*)p; p += (size_t)3072 * 1024 * 2;    // 6.3 MB
  unsigned short* Wob  = (unsigned short*)p; p += (size_t)1024 * 1024 * 2;    // 2 MB
  float* bqkv = (float*)p; p += 3072 * 4;
  float* bob  = (float*)p; p += 1024 * 4;
  unsigned short* qkv = (unsigned short*)p; p += (size_t)3 * 16777216 * 2;    // 100.6 MB
  unsigned short* ctx = (unsigned short*)p; p += (size_t)16777216 * 2;        // 33.5 MB

  // 1/sqrt(64) * log2(e) folded into q weights+bias -> softmax in base 2
  const float qscale = 0.125f * 1.4426950408889634f;

  cast_x<<<16384, 256, 0, stream>>>(hs, xbf, 16777216 / 4);
  prep_weights<<<1024, 256, 0, stream>>>(Wq, bq, LMq, RMq, Fq, qscale, Wqkv, bqkv);
  prep_weights<<<1024, 256, 0, stream>>>(Wk, bk, LMk, RMk, Fk, 1.0f, Wqkv + 1024 * 1024, bqkv + 1024);
  prep_weights<<<1024, 256, 0, stream>>>(Wv, bv, LMv, RMv, Fv, 1.0f, Wqkv + 2 * 1024 * 1024, bqkv + 2048);
  prep_weights<<<1024, 256, 0, stream>>>(Wo, bo, LMo, RMo, Fo, 1.0f, Wob, bob);

  // 1D grids, XCD-chunked decode inside (nwg % 8 == 0 for both)
  gemm_bt<0><<<3072, 256, 0, stream>>>(xbf, Wqkv, bqkv, (void*)qkv, 16384, 3072, 1024);

  attn<<<2048, 256, 0, stream>>>(qkv, qkv + 16777216, qkv + 2 * 16777216, ctx);

  gemm_bt<1><<<1024, 256, 0, stream>>>(ctx, Wob, bob, d_out, 16384, 1024, 1024);
}

// Round 4
// 467.014 us; speedup vs baseline: 1.0851x; 1.0851x over previous
//
#include <hip/hip_runtime.h>
#include <cstdint>
#include <cstddef>

typedef short short8 __attribute__((ext_vector_type(8)));
typedef float f32x4 __attribute__((ext_vector_type(4)));
typedef float f32x16 __attribute__((ext_vector_type(16)));
typedef unsigned short us4 __attribute__((ext_vector_type(4)));

// ---------- helpers ----------
__device__ __forceinline__ unsigned short f2bf(float f) {
  unsigned int u = __float_as_uint(f);
  unsigned int r = (u + 0x7fffu + ((u >> 16) & 1u)) >> 16;  // RNE
  return (unsigned short)r;
}
// v_exp_f32: D = 2^S0 (builtin; __exp2f collides with glibc math.h here)
__device__ __forceinline__ float exp2_fast(float x) {
  return __builtin_amdgcn_exp2f(x);
}
// gfx950 packed f32->bf16 RNE convert: D[15:0]=bf16(a), D[31:16]=bf16(b)
__device__ __forceinline__ unsigned int cvt_pk_bf16(float a, float b) {
  unsigned int d;
  asm("v_cvt_pk_bf16_f32 %0, %1, %2" : "=v"(d) : "v"(a), "v"(b));
  return d;
}
// v_permlane32_swap_b32 a, b : a(upper 32 lanes) <-> b(lower 32 lanes).
__device__ __forceinline__ void permlane32_swap2(unsigned int& a, unsigned int& b) {
  asm("v_permlane32_swap_b32 %0, %1" : "+v"(a), "+v"(b));
}
// async global->LDS, 16B per lane. LDS dest = wave-uniform base + lane*16.
__device__ __forceinline__ void gload_lds16(const void* g, void* l) {
  auto gp = reinterpret_cast<const __attribute__((address_space(1))) char*>(
      reinterpret_cast<uintptr_t>(g));
  auto lp = reinterpret_cast<__attribute__((address_space(3))) char*>(
      reinterpret_cast<uintptr_t>(l));
  __builtin_amdgcn_global_load_lds(gp, lp, 16, 0, 0);
}

// ---------- weight reconstruction: w' = (LM@RM + W) * F * scale (bf16), b' = b*F*scale ----------
__global__ __launch_bounds__(256) void prep_weights(
    const float* __restrict__ W, const float* __restrict__ bias,
    const float* __restrict__ LM, const float* __restrict__ RM,
    const float* __restrict__ F, float scale,
    unsigned short* __restrict__ Wout, float* __restrict__ bout) {
  const int o = blockIdx.x;      // output row 0..1023
  const int tid = threadIdx.x;   // 256
  __shared__ float lm[64];
  if (tid < 64) lm[tid] = LM[o * 64 + tid];
  __syncthreads();
  const float f = F[o] * scale;
#pragma unroll
  for (int j = 0; j < 4; ++j) {
    const int i = tid + j * 256;
    float acc = W[o * 1024 + i];
#pragma unroll 16
    for (int k = 0; k < 64; ++k) acc = fmaf(lm[k], RM[k * 1024 + i], acc);
    Wout[o * 1024 + i] = f2bf(acc * f);
  }
  if (tid == 0) bout[o] = bias[o] * f;
}

// ---------- f32 -> bf16 cast ----------
__global__ __launch_bounds__(256) void cast_x(const float* __restrict__ x,
                                              unsigned short* __restrict__ y, int n4) {
  const int i = blockIdx.x * 256 + threadIdx.x;
  if (i >= n4) return;
  f32x4 v = *(const f32x4*)(x + (size_t)i * 4);
  us4 o;
  o[0] = f2bf(v[0]); o[1] = f2bf(v[1]); o[2] = f2bf(v[2]); o[3] = f2bf(v[3]);
  *(us4*)(y + (size_t)i * 4) = o;
}

// ---------- GEMM: C[m][n] = sum_k A[m][k]*Bw[n][k] + bias[n] ----------
// R9: L3-supertile decode (group of 8 bm panels x all bn; A-group 2MB + B 6.3MB
// stay L3-resident -> A fetched ~once). Dbuf with single barrier per K-tile:
// front-load all 16 frag ds_reads -> stage(t+1) -> MFMA cluster -> vmcnt(0)
// (issued one full MFMA phase earlier => ~free) -> barrier.
// Hazards: stage(t+1->b^1) issued iter t; b^1's reads ended before iter t-1's
// trailing barrier. stage lands gated by trailing vmcnt(0)+barrier of iter t.
// 128x128 block tile, BK=64, 4 waves each 64x64 (4x4 of 16x16x32 mfma).
// LDS XOR-swizzled: 16B chunk c of row r stored at chunk position c^(r&7).
// MODE 0: scatter to qkv bf16: q,k -> [bh][s][d]; v -> TRANSPOSED [bh][d][s].
// MODE 1: f32 row-major out.
template <int MODE>
__global__ __launch_bounds__(256) void gemm_bt(const unsigned short* __restrict__ A,
                                               const unsigned short* __restrict__ Bw,
                                               const float* __restrict__ bias,
                                               void* __restrict__ Cout,
                                               int M, int N, int K) {
  __shared__ unsigned short sA[2][128 * 64];
  __shared__ unsigned short sB[2][128 * 64];
  const int tid = threadIdx.x;
  const int w = tid >> 6;
  const int lane = tid & 63;
  const int quad = lane >> 4;
  const int ln = lane & 15;
  // L3-supertile decode: groups of 8 bm panels; bn sweeps fastest inside group.
  const int nbn = N >> 7;
  const int bid = (int)blockIdx.x;
  const int grp = bid / (nbn * 8);
  const int rem = bid - grp * (nbn * 8);
  const int bn = rem >> 3;
  const int bm = grp * 8 + (rem & 7);
  const int wm = w >> 1, wn = w & 1;

  f32x4 acc[4][4];
#pragma unroll
  for (int a = 0; a < 4; ++a)
#pragma unroll
    for (int b = 0; b < 4; ++b) acc[a][b] = (f32x4){0.f, 0.f, 0.f, 0.f};

  const size_t Kb = (size_t)K * 2;
  const char* Agb = (const char*)A + (size_t)bm * 128 * Kb;
  const char* Bgb = (const char*)Bw + (size_t)bn * 128 * Kb;
  const int sw = ln & 7;
  const int nt = K >> 6;

  // stage K-tile (64 k) starting at element k-offset k0 into buffer buf
  auto stage = [&](int k0, int buf) {
    char* sAd = (char*)sA + buf * 16384;
    char* sBd = (char*)sB + buf * 16384;
#pragma unroll
    for (int i = 0; i < 4; ++i) {
      const int Lb = w * 4096 + i * 1024 + lane * 16;  // linear byte in tile
      const int r = Lb >> 7;                           // tile row (128B rows)
      const int c = (Lb >> 4) & 7;                     // LDS chunk slot
      const int cb = ((c ^ (r & 7)) * 16);             // global chunk (unswizzle)
      gload_lds16(Agb + (size_t)r * Kb + (size_t)k0 * 2 + cb, sAd + Lb);
      gload_lds16(Bgb + (size_t)r * Kb + (size_t)k0 * 2 + cb, sBd + Lb);
    }
  };

  stage(0, 0);  // prologue
  asm volatile("s_waitcnt vmcnt(0)" ::: "memory");
  __builtin_amdgcn_s_barrier();

  for (int t = 0; t < nt; ++t) {
    const int cur = t & 1;
    const char* sAc = (const char*)sA + cur * 16384;
    const char* sBc = (const char*)sB + cur * 16384;

    // front-load all fragment reads for this K-tile into registers
    short8 af[2][4], bfv[2][4];
#pragma unroll
    for (int kk = 0; kk < 2; ++kk)
#pragma unroll
      for (int t4 = 0; t4 < 4; ++t4) {
        const int ch = ((kk * 4 + quad) ^ sw) * 16;
        af[kk][t4]  = *(const short8*)(sAc + (wm * 64 + t4 * 16 + ln) * 128 + ch);
        bfv[kk][t4] = *(const short8*)(sBc + (wn * 64 + t4 * 16 + ln) * 128 + ch);
      }

    // prefetch next K-tile into the other buffer (b^1 free since iter t-1)
    if (t + 1 < nt) stage((t + 1) << 6, cur ^ 1);

    // MFMA cluster (compiler inserts lgkmcnt for the frag reads)
    __builtin_amdgcn_s_setprio(1);
#pragma unroll
    for (int kk = 0; kk < 2; ++kk)
#pragma unroll
      for (int mt = 0; mt < 4; ++mt)
#pragma unroll
        for (int ntc = 0; ntc < 4; ++ntc)
          acc[mt][ntc] = __builtin_amdgcn_mfma_f32_16x16x32_bf16(af[kk][mt], bfv[kk][ntc], acc[mt][ntc], 0, 0, 0);
    __builtin_amdgcn_s_setprio(0);

    // stage(t+1) landed? issued one full MFMA phase ago -> ~free drain.
    asm volatile("s_waitcnt vmcnt(0)" ::: "memory");
    __builtin_amdgcn_s_barrier();  // stage(t+1) visible; buf[cur] reads done block-wide
    asm volatile("" ::: "memory");
  }

  // epilogue. C/D layout: col = ln, row = quad*4 + reg (measured m89/m91)
  if (MODE == 0) {
    unsigned short* out = (unsigned short*)Cout;
#pragma unroll
    for (int mt = 0; mt < 4; ++mt) {
#pragma unroll
      for (int ntc = 0; ntc < 4; ++ntc) {
        const int gn = bn * 128 + wn * 64 + ntc * 16 + ln;
        const float bv = bias[gn];
        const int pidx = gn >> 10, rem2 = gn & 1023;
        const int hh = rem2 >> 6, dd = rem2 & 63;
        const int gm0 = bm * 128 + wm * 64 + mt * 16 + quad * 4;
        const int bb = gm0 >> 10, ss0 = gm0 & 1023;
        if (pidx < 2) {
          // q,k: [p][b][h][s][d]
#pragma unroll
          for (int r = 0; r < 4; ++r) {
            const size_t off = ((((size_t)pidx * 16 + bb) * 16 + hh) * 1024 + (ss0 + r)) * 64 + dd;
            out[off] = f2bf(acc[mt][ntc][r] + bv);
          }
        } else {
          // v: transposed [b][h][d][s]; r -> consecutive s -> one 8B store
          us4 pk;
#pragma unroll
          for (int r = 0; r < 4; ++r) pk[r] = f2bf(acc[mt][ntc][r] + bv);
          const size_t off = (size_t)2 * 16777216 +
                             (((size_t)(bb * 16 + hh) * 64 + dd) * 1024 + ss0);
          *(us4*)(out + off) = pk;
        }
      }
    }
  } else {
    float* out = (float*)Cout;
#pragma unroll
    for (int mt = 0; mt < 4; ++mt) {
#pragma unroll
      for (int ntc = 0; ntc < 4; ++ntc) {
        const int gn = bn * 128 + wn * 64 + ntc * 16 + ln;
        const float bv = bias[gn];
#pragma unroll
        for (int r = 0; r < 4; ++r) {
          const int gm = bm * 128 + wm * 64 + mt * 16 + quad * 4 + r;
          out[(size_t)gm * N + gn] = acc[mt][ntc][r] + bv;
        }
      }
    }
  }
}

// ---------- flash attention, 32x32 MFMA, in-register P (T12), dbuf K/V ----------
// (unchanged from R7)
__global__ __launch_bounds__(256) void attn(const unsigned short* __restrict__ Qb,
                                            const unsigned short* __restrict__ Kb_,
                                            const unsigned short* __restrict__ VTb,
                                            unsigned short* __restrict__ ctx) {
  __shared__ unsigned short sK[2][64 * 64];   // [buf][kv][d], 128B rows, swizzled chunks
  __shared__ unsigned short sVT[2][64 * 64];  // [buf][d][kv], 128B rows, swizzled chunks
  const int tid = threadIdx.x;
  const int w = tid >> 6, lane = tid & 63;
  const int col = lane & 31, hi = lane >> 5;  // col = q (QK) / d (PV), hi = k-group
  const int sw7 = col & 7;                    // row&7 for swizzled LDS reads
  const int bid = blockIdx.x;
  const int xcd = bid & 7, qt = (bid >> 3) & 7, sbh = bid >> 6;
  const int bh = xcd * 32 + sbh;
  const int b = bh >> 4, h = bh & 15;

  // Q fragments (B-operand), loop-invariant: col=q, k = d = ks*16 + hi*8 + j
  short8 bq[4];
  {
    const unsigned short* Qg =
        Qb + ((size_t)bh * 1024 + (size_t)qt * 128 + w * 32 + col) * 64 + hi * 8;
#pragma unroll
    for (int ks = 0; ks < 4; ++ks) bq[ks] = *(const short8*)(Qg + ks * 16);
  }

  f32x16 accO[2];
#pragma unroll
  for (int nt = 0; nt < 2; ++nt)
#pragma unroll
    for (int r = 0; r < 16; ++r) accO[nt][r] = 0.f;
  float mrun = -3e38f, lrun = 0.f;

  const char* Kbase = (const char*)Kb_ + (size_t)bh * 131072;  // [kv=1024][d=64] bf16
  const char* Vbase = (const char*)VTb + (size_t)bh * 131072;  // [d=64][kv=1024] bf16

  // issue 4 gload_lds (K,V interleaved) for tile kt into buffer buf
  auto stage = [&](int kt, int buf) {
#pragma unroll
    for (int i = 0; i < 2; ++i) {
      const int Lb = w * 2048 + i * 1024 + lane * 16;
      const int r = Lb >> 7;            // tile row (128B rows)
      const int c = (Lb >> 4) & 7;      // LDS chunk slot
      const int cb = ((c ^ (r & 7)) * 16);
      gload_lds16(Kbase + (size_t)kt * 8192 + (size_t)r * 128 + cb, (char*)sK[buf] + Lb);
      gload_lds16(Vbase + (size_t)kt * 128 + (size_t)r * 2048 + cb, (char*)sVT[buf] + Lb);
    }
  };

  stage(0, 0);  // prologue: 4 loads in flight

  for (int kt = 0; kt < 16; ++kt) {
    const int cur = kt & 1;
    const char* sKb = (const char*)sK[cur];
    const char* sVb = (const char*)sVT[cur];

    // prefetch next tile into the other buffer (wraps harmlessly at kt=15)
    stage((kt + 1) & 15, cur ^ 1);
    // wait for OWN stage(kt) (4 oldest of 8 outstanding); prefetch stays in flight
    asm volatile("s_waitcnt vmcnt(4)" ::: "memory");
    __builtin_amdgcn_s_barrier();  // all waves' stage(kt) landed
    asm volatile("" ::: "memory");

    // S^T: A = K[kv][d], B = Q (col=q). accS[mt]: col=q, row=kv within mt*32.
    f32x16 accS[2];
#pragma unroll
    for (int mt = 0; mt < 2; ++mt)
#pragma unroll
      for (int r = 0; r < 16; ++r) accS[mt][r] = 0.f;
#pragma unroll
    for (int ks = 0; ks < 4; ++ks) {
      const int ch = (((2 * ks + hi) ^ sw7) * 16);
      const short8 ak0 = *(const short8*)(sKb + (col)*128 + ch);
      const short8 ak1 = *(const short8*)(sKb + (32 + col) * 128 + ch);
      __builtin_amdgcn_s_setprio(1);
      accS[0] = __builtin_amdgcn_mfma_f32_32x32x16_bf16(ak0, bq[ks], accS[0], 0, 0, 0);
      accS[1] = __builtin_amdgcn_mfma_f32_32x32x16_bf16(ak1, bq[ks], accS[1], 0, 0, 0);
      __builtin_amdgcn_s_setprio(0);
    }

    // online softmax (base-2; q pre-scaled by log2e/8). Lane: q=col,
    // kv = mt*32 + (r&3)+8*(r>>2)+4*hi.
    float tmax = -3e38f;
#pragma unroll
    for (int mt = 0; mt < 2; ++mt)
#pragma unroll
      for (int r = 0; r < 16; ++r) tmax = fmaxf(tmax, accS[mt][r]);
    tmax = fmaxf(tmax, __shfl_xor(tmax, 32));
    // defer-max: only rescale when the tile max meaningfully exceeds mrun.
    if (!__all(tmax <= mrun + 8.0f)) {
      const float mnew = fmaxf(mrun, tmax);
      const float alpha = exp2_fast(mrun - mnew);
      mrun = mnew;
      lrun *= alpha;
#pragma unroll
      for (int r = 0; r < 16; ++r) {
        const float ar = __shfl(alpha, (r & 3) + 8 * (r >> 2) + 4 * hi);
        accO[0][r] *= ar;
        accO[1][r] *= ar;
      }
    }
    const float m = mrun;

    // P chunks: exp2 -> bf16 pack -> permlane assemble A-frag -> PV MFMA.
    float psum = 0.f;
#pragma unroll
    for (int mt = 0; mt < 2; ++mt) {
#pragma unroll
      for (int c = 0; c < 2; ++c) {
        const int r0 = c * 8;
        const float e0 = exp2_fast(accS[mt][r0 + 0] - m);
        const float e1 = exp2_fast(accS[mt][r0 + 1] - m);
        const float e2 = exp2_fast(accS[mt][r0 + 2] - m);
        const float e3 = exp2_fast(accS[mt][r0 + 3] - m);
        const float e4 = exp2_fast(accS[mt][r0 + 4] - m);
        const float e5 = exp2_fast(accS[mt][r0 + 5] - m);
        const float e6 = exp2_fast(accS[mt][r0 + 6] - m);
        const float e7 = exp2_fast(accS[mt][r0 + 7] - m);
        psum += ((e0 + e1) + (e2 + e3)) + ((e4 + e5) + (e6 + e7));
        unsigned int x = cvt_pk_bf16(e0, e1);
        unsigned int y = cvt_pk_bf16(e2, e3);
        unsigned int z = cvt_pk_bf16(e4, e5);
        unsigned int t = cvt_pk_bf16(e6, e7);
        permlane32_swap2(x, z);  // -> x = dw0 (k=hi*8+0,1), z = dw2 (k=hi*8+4,5)
        permlane32_swap2(y, t);  // -> y = dw1 (k=hi*8+2,3), t = dw3 (k=hi*8+6,7)
        union { unsigned int u[4]; short8 v; } pa;
        pa.u[0] = x; pa.u[1] = y; pa.u[2] = z; pa.u[3] = t;
        const int cs = mt * 4 + c * 2 + hi;
        const int ch = ((cs ^ sw7) * 16);
        const short8 bv0 = *(const short8*)(sVb + (col)*128 + ch);
        const short8 bv1 = *(const short8*)(sVb + (32 + col) * 128 + ch);
        __builtin_amdgcn_s_setprio(1);
        accO[0] = __builtin_amdgcn_mfma_f32_32x32x16_bf16(pa.v, bv0, accO[0], 0, 0, 0);
        accO[1] = __builtin_amdgcn_mfma_f32_32x32x16_bf16(pa.v, bv1, accO[1], 0, 0, 0);
        __builtin_amdgcn_s_setprio(0);
      }
    }
    lrun += psum;  // per-lane partial (lanes l, l^32 hold disjoint kv halves)

    __builtin_amdgcn_s_barrier();  // all waves done reading buf[cur]
    asm volatile("" ::: "memory");
  }

  // epilogue: ctx[b][sg][h*64+d] bf16. accO: col=d (nt*32+col), row=q.
  float lt = lrun + __shfl_xor(lrun, 32);
  const float inv = 1.0f / lt;
#pragma unroll
  for (int r = 0; r < 16; ++r) {
    const int qr = (r & 3) + 8 * (r >> 2) + 4 * hi;
    const float iv = __shfl(inv, qr);  // lane qr holds inv for q=qr
    const int sg = qt * 128 + w * 32 + qr;
    const size_t base = ((size_t)(b * 1024 + sg)) * 1024 + h * 64;
    ctx[base + col] = f2bf(accO[0][r] * iv);
    ctx[base + 32 + col] = f2bf(accO[1][r] * iv);
  }
}

// ---------- launch ----------
extern "C" void kernel_launch(void* const* d_in, const int* in_sizes, int n_in,
                              void* d_out, int out_size, void* d_ws, size_t ws_size,
                              hipStream_t stream) {
  const float* hs  = (const float*)d_in[0];
  const float* Wq  = (const float*)d_in[1];
  const float* bq  = (const float*)d_in[2];
  const float* LMq = (const float*)d_in[3];
  const float* RMq = (const float*)d_in[4];
  const float* Fq  = (const float*)d_in[5];
  const float* Wk  = (const float*)d_in[6];
  const float* bk  = (const float*)d_in[7];
  const float* LMk = (const float*)d_in[8];
  const float* RMk = (const float*)d_in[9];
  const float* Fk  = (const float*)d_in[10];
  const float* Wv  = (const float*)d_in[11];
  const float* bv  = (const float*)d_in[12];
  const float* LMv = (const float*)d_in[13];
  const float* RMv = (const float*)d_in[14];
  const float* Fv  = (const float*)d_in[15];
  const float* Wo  = (const float*)d_in[16];
  const float* bo  = (const float*)d_in[17];
  const float* LMo = (const float*)d_in[18];
  const float* RMo = (const float*)d_in[19];
  const float* Fo  = (const float*)d_in[20];
  // d_in[21] = task (always 0 branch in reference)

  // workspace layout (all 16B aligned)
  char* p = (char*)d_ws;
  unsigned short* xbf  = (unsigned short*)p; p += (size_t)16384 * 1024 * 2;   // 33.5 MB
  unsigned short* Wqkv = (unsigned short*)p; p += (size_t)3072 * 1024 * 2;    // 6.3 MB
  unsigned short* Wob  = (unsigned short*)p; p += (size_t)1024 * 1024 * 2;    // 2 MB
  float* bqkv = (float*)p; p += 3072 * 4;
  float* bob  = (float*)p; p += 1024 * 4;
  unsigned short* qkv = (unsigned short*)p; p += (size_t)3 * 16777216 * 2;    // 100.6 MB
  unsigned short* ctx = (unsigned short*)p; p += (size_t)16777216 * 2;        // 33.5 MB

  // 1/sqrt(64) * log2(e) folded into q weights+bias -> softmax in base 2
  const float qscale = 0.125f * 1.4426950408889634f;

  cast_x<<<16384, 256, 0, stream>>>(hs, xbf, 16777216 / 4);
  prep_weights<<<1024, 256, 0, stream>>>(Wq, bq, LMq, RMq, Fq, qscale, Wqkv, bqkv);
  prep_weights<<<1024, 256, 0, stream>>>(Wk, bk, LMk, RMk, Fk, 1.0f, Wqkv + 1024 * 1024, bqkv + 1024);
  prep_weights<<<1024, 256, 0, stream>>>(Wv, bv, LMv, RMv, Fv, 1.0f, Wqkv + 2 * 1024 * 1024, bqkv + 2048);
  prep_weights<<<1024, 256, 0, stream>>>(Wo, bo, LMo, RMo, Fo, 1.0f, Wob, bob);

  // 1D grids, L3-supertile decode inside
  gemm_bt<0><<<3072, 256, 0, stream>>>(xbf, Wqkv, bqkv, (void*)qkv, 16384, 3072, 1024);

  attn<<<2048, 256, 0, stream>>>(qkv, qkv + 16777216, qkv + 2 * 16777216, ctx);

  gemm_bt<1><<<1024, 256, 0, stream>>>(ctx, Wob, bob, d_out, 16384, 1024, 1024);
}